// Round 3
// baseline (259.422 us; speedup 1.0000x reference)
//
#include <hip/hip_runtime.h>
#include <hip/hip_bf16.h>
#include <stdint.h>

// MMoE: E=16 experts, T=4 tasks, H=512, I=1024, B=8192.
// out[t,b] = sum_e g[b,t,e] * (sum_h relu(x@We^T+be)[b,e,h] * Wf[t,h]) + bf[t]
//
// R16: single-barrier 4-deep-ring K-loop. R14/R15 both pinned at MfmaUtil
// ~40%: in the 8-phase double-barrier schedule, LDS fragment reads
// (192 KB/K-tile, ~1500-2300 cyc) and MFMA windows (~2060 cyc) are in
// mutually-exclusive barrier regions -> their SUM (~4400-4700 cyc/K-tile)
// matches the measured 140-148 us. Fix: BK=32, 4 LDS buffers (4 x 32 KB =
// 128 KB), prefetch depth 3, ONE s_barrier per K-tile. Reads + 32 MFMAs
// live in one unbroken region -> compiler interleaves (its verified
// strength), LDS-read time hides under MFMA time.
// Safety proof for 1 barrier/window: stage at window t targets
// buf[(t+3)&3] = buffer last read at window t-1; every wave executes
// s_waitcnt lgkmcnt(0) at window end (REQUIRED: a compiler-sunk MFMA would
// otherwise let a ds_read stay in flight across the barrier) and
// s_waitcnt vmcnt(8) before the barrier (own stages for tile t complete);
// barrier then implies: all waves' reads of buf[(t-1)&3] done AND all
// waves' stages of tile t landed. Counted vmcnt(8) = 2 tiles in flight
// across the barrier; vmcnt never 0 except the peeled tail windows.
// R15 persistence reverted (FETCH +25%, A re-fetch, no MfmaUtil gain).
// R13 invariant kept: blockIdx.x = mb -> concurrent blocks hit disjoint
// out rows, no atomic collision.

#define E_ 16
#define T_ 4
#define H_ 512
#define I_ 1024
#define B_ 8192
#define N_ (E_ * H_) /* 8192 */
#define K_ I_        /* 1024 */

typedef __bf16 bf16x8 __attribute__((ext_vector_type(8)));
typedef float f32x4 __attribute__((ext_vector_type(4)));

__device__ __forceinline__ unsigned short f2bf_rne(float f) {
  unsigned int b = __float_as_uint(f);
  b += 0x7fffu + ((b >> 16) & 1u);
  return (unsigned short)(b >> 16);
}

#define N4X (B_ * K_ / 4) /* 2097152 */
#define N4W (N_ * K_ / 4) /* 2097152 */
#define N4G (64 * K_ / 4) /* 16384 */

// merged fp32 -> bf16 (RNE) for x | We | Wg, float4 in / ushort4 out.
// First T_*B_ threads also initialize out[t*B+b] = bf[t] (atomic-accumulated
// by moe_main later; harness re-poisons out before every launch).
__global__ __launch_bounds__(256) void cvt3_kernel(const float* __restrict__ x,
                                                   const float* __restrict__ We,
                                                   const float* __restrict__ Wg,
                                                   const float* __restrict__ bfv,
                                                   unsigned short* __restrict__ xb,
                                                   unsigned short* __restrict__ wb,
                                                   unsigned short* __restrict__ wgb,
                                                   float* __restrict__ out) {
  int i = blockIdx.x * 256 + threadIdx.x;
  if (i < T_ * B_) out[i] = bfv[i >> 13];  // t = i / 8192
  const float* src;
  unsigned short* dst;
  int j;
  if (i < N4X) {
    src = x; dst = xb; j = i;
  } else if (i < N4X + N4W) {
    src = We; dst = wb; j = i - N4X;
  } else if (i < N4X + N4W + N4G) {
    src = Wg; dst = wgb; j = i - (N4X + N4W);
  } else {
    return;
  }
  float4 v = reinterpret_cast<const float4*>(src)[j];
  ushort4 o;
  o.x = f2bf_rne(v.x);
  o.y = f2bf_rne(v.y);
  o.z = f2bf_rne(v.z);
  o.w = f2bf_rne(v.w);
  reinterpret_cast<ushort4*>(dst)[j] = o;
}

__device__ __forceinline__ void gld_lds16(const void* gp, void* lp) {
  __builtin_amdgcn_global_load_lds((const __attribute__((address_space(1))) void*)gp,
                                   (__attribute__((address_space(3))) void*)lp, 16, 0, 0);
}

// logits L[b][te] = x[b,:]@Wg[te,:] + bg[te] via bf16 MFMA (Wg [T][E][I] is
// already B^T [64][1024]), then softmax over e (= the 16 m16-lanes) in
// registers -> g[b][64]. Tile: M=128, N=64, BK=32; 4 waves x 32 rows each.
__global__ __launch_bounds__(256) void logits_softmax_kernel(
    const unsigned short* __restrict__ A,    // x bf16 [B_][K_]
    const unsigned short* __restrict__ Bm,   // Wg bf16 [64][K_]
    const float* __restrict__ bg,            // [64]
    float* __restrict__ g)                   // [B_][64]
{
  __shared__ struct {
    unsigned short A[128 * 32];  // 8 KB
    unsigned short B[64 * 32];   // 4 KB
  } st;

  const int tid = threadIdx.x;
  const int w = tid >> 6, l = tid & 63;
  const int m16 = l & 15, q = l >> 4;
  const size_t m0 = (size_t)blockIdx.x * 128;

  // A staging: rows w*32..w*32+31, 2 chunks/thread
  const int r0s = (w * 2 + 0) * 16 + (l >> 2);
  const int r1s = (w * 2 + 1) * 16 + (l >> 2);
  const int slot = l & 3;
  const int c0 = slot ^ ((r0s >> 1) & 3);
  const int c1 = slot ^ ((r1s >> 1) & 3);
  const size_t offA0 = (m0 + r0s) * K_ + c0 * 8;
  const size_t offA1 = (m0 + r1s) * K_ + c1 * 8;
  const int l0 = (w * 2 + 0) * 512;
  const int l1 = (w * 2 + 1) * 512;
  // B staging: 64 rows, 1 chunk/thread; wave w covers rows w*16..w*16+15
  const int rBs = w * 16 + (l >> 2);
  const int cB = slot ^ ((rBs >> 1) & 3);
  const size_t offB = (size_t)rBs * K_ + cB * 8;
  const int lB = w * 512;

  const int arow = w * 32 + m16;
  const int sA = q ^ ((arow >> 1) & 3);
  const int sB = q ^ ((m16 >> 1) & 3);

  f32x4 acc[2][4] = {};

  for (int k0 = 0; k0 < K_; k0 += 32) {
    __syncthreads();
    gld_lds16(A + offA0 + k0, st.A + l0);
    gld_lds16(A + offA1 + k0, st.A + l1);
    gld_lds16(Bm + offB + k0, st.B + lB);
    __syncthreads();
    bf16x8 af[2], bfr[4];
#pragma unroll
    for (int i = 0; i < 2; ++i)
      af[i] = *reinterpret_cast<const bf16x8*>(st.A + (arow + i * 16) * 32 + sA * 8);
#pragma unroll
    for (int j = 0; j < 4; ++j)
      bfr[j] = *reinterpret_cast<const bf16x8*>(st.B + (j * 16 + m16) * 32 + sB * 8);
#pragma unroll
    for (int i = 0; i < 2; ++i)
#pragma unroll
      for (int j = 0; j < 4; ++j)
        acc[i][j] = __builtin_amdgcn_mfma_f32_16x16x32_bf16(af[i], bfr[j], acc[i][j], 0, 0, 0);
  }

  // acc[i][j][r] = L[row = w*32+16i+4q+r][te = j*16+m16]; t = j, e = m16.
  float bgv[4];
#pragma unroll
  for (int j = 0; j < 4; ++j) bgv[j] = bg[j * 16 + m16];

#pragma unroll
  for (int i = 0; i < 2; ++i) {
    float lg[4][4];  // [r][j]
#pragma unroll
    for (int j = 0; j < 4; ++j)
#pragma unroll
      for (int r = 0; r < 4; ++r) lg[r][j] = acc[i][j][r] + bgv[j];
#pragma unroll
    for (int r = 0; r < 4; ++r) {
#pragma unroll
      for (int j = 0; j < 4; ++j) {
        float m = lg[r][j];
#pragma unroll
        for (int mask = 1; mask < 16; mask <<= 1) m = fmaxf(m, __shfl_xor(m, mask, 64));
        float ex = __expf(lg[r][j] - m);
        float s = ex;
#pragma unroll
        for (int mask = 1; mask < 16; mask <<= 1) s += __shfl_xor(s, mask, 64);
        size_t b = m0 + w * 32 + i * 16 + q * 4 + r;
        g[b * 64 + j * 16 + m16] = ex / s;
      }
    }
  }
}

// ---------------- 256^2 single-barrier 4-ring main kernel ----------------

extern __shared__ char smem[];  // 131072 B: ring buf b at b*32768; A +0, B +16384

#define BARRIER()                          \
  do {                                     \
    asm volatile("" ::: "memory");         \
    __builtin_amdgcn_s_barrier();          \
    asm volatile("" ::: "memory");         \
  } while (0)
#define VMW(n) asm volatile("s_waitcnt vmcnt(" #n ")" ::: "memory")
#define LGKM0() asm volatile("s_waitcnt lgkmcnt(0)" ::: "memory")

// stage K-tile t (256 rows x 32 k of A and B) into ring buf t&3.
// Per wave: 2 gld for A (16 rows x 64 B each) + 2 for B. LDS dest is
// wave-uniform (HW adds lane*16); global src carries the swizzle
// chunk c = (l&3) ^ ((l>>3)&3)  (== (l&3) ^ ((row>>1)&3) for this mapping).
#define STAGE4(t_)                                                             \
  do {                                                                         \
    const int bb_ = ((t_) & 3) * 32768;                                        \
    const int ko_ = (t_) * 32;                                                 \
    gld_lds16(A + baseAg + ko_, smem + bb_ + ldsW);                            \
    gld_lds16(A + baseAg + 16 * K_ + ko_, smem + bb_ + ldsW + 1024);           \
    gld_lds16(Bm + baseBg + ko_, smem + bb_ + 16384 + ldsW);                   \
    gld_lds16(Bm + baseBg + 16 * K_ + ko_, smem + bb_ + 16384 + ldsW + 1024);  \
  } while (0)

// one K-tile: 12 ds_read_b128 + 32 MFMA in ONE region — compiler interleaves
// (fine-grained lgkmcnt), LDS-read latency hides under MFMA.
#define COMPUTE(t_)                                                                     \
  do {                                                                                  \
    const int bb_ = ((t_) & 3) * 32768;                                                 \
    bf16x8 af[8], bfr[4];                                                               \
    _Pragma("unroll") for (int i = 0; i < 8; ++i) af[i] =                               \
        *reinterpret_cast<const bf16x8*>(smem + bb_ + baseA_rd + i * 1024 + sl16);      \
    _Pragma("unroll") for (int j = 0; j < 4; ++j) bfr[j] =                              \
        *reinterpret_cast<const bf16x8*>(smem + bb_ + 16384 + baseB_rd + j * 1024 + sl16); \
    __builtin_amdgcn_s_setprio(1);                                                      \
    _Pragma("unroll") for (int i = 0; i < 8; ++i)                                       \
        _Pragma("unroll") for (int j = 0; j < 4; ++j)                                   \
            acc[i][j] = __builtin_amdgcn_mfma_f32_16x16x32_bf16(af[i], bfr[j],          \
                                                                acc[i][j], 0, 0, 0);   \
    __builtin_amdgcn_s_setprio(0);                                                      \
  } while (0)

__global__ __launch_bounds__(512, 2) void moe_main_kernel(
    const unsigned short* __restrict__ A,   // x bf16 [B_][K_]
    const unsigned short* __restrict__ Bm,  // We bf16 [N_][K_]
    const float* __restrict__ be,           // [E_*H_] flat == indexed by n
    const float* __restrict__ Wf,           // [T_][H_]
    const float* __restrict__ g,            // [B_][64] (t*16+e)
    float* __restrict__ out)                // [T_][B_] (pre-init to bf[t])
{
  const int tid = threadIdx.x;
  const int w = tid >> 6, l = tid & 63;
  const int wm = w >> 2, wn = w & 3;  // 2 M-waves x 4 N-waves; wave tile 128x64
  const int m16 = l & 15, q = l >> 4;
  const int mb = blockIdx.x, nb = blockIdx.y;  // x=mb: decorrelate atomics (R13)
  const size_t m0 = (size_t)mb * 256, n0 = (size_t)nb * 256;

  // global staging bases (elements); lane covers row w*32 + (l>>2) (+16 for
  // the 2nd gld), chunk c8 = ((l&3) ^ ((l>>3)&3)) * 8.
  const int c8 = (((l & 3) ^ ((l >> 3) & 3)) * 8);
  const size_t baseAg = (m0 + w * 32 + (l >> 2)) * K_ + c8;
  const size_t baseBg = (n0 + w * 32 + (l >> 2)) * K_ + c8;
  const int ldsW = w * 2048;  // (w*32 rows) * 64 B

  // ds_read addressing: row r at byte r*64; 16B slot q ^ ((r>>1)&3); for all
  // fragment rows (r>>1)&3 == (m16>>1)&3 (row-base multiples of 16 drop out).
  const int sl16 = (q ^ ((m16 >> 1) & 3)) * 16;
  const int baseA_rd = (wm * 128 + m16) * 64;
  const int baseB_rd = (wn * 64 + m16) * 64;

  f32x4 acc[8][4] = {};

  // prologue: prime ring with tiles 0,1,2 (12 loads/thread outstanding)
  STAGE4(0);
  STAGE4(1);
  STAGE4(2);

  // window t: VMW(8) [own tile-t stages done] -> barrier [all waves' tile-t
  // stages done; all waves' reads of buf[(t-1)&3] done] -> stage t+3 into
  // buf[(t-1)&3] -> 12 reads + 32 MFMA -> lgkmcnt(0) [reads off the wire
  // before next barrier]. Ledger: 12 outstanding at VMW, 8 after, 12 again
  // after stage.
#pragma unroll 1
  for (int t = 0; t < 29; ++t) {
    VMW(8);
    BARRIER();
    STAGE4(t + 3);
    COMPUTE(t);
    LGKM0();
  }
  // peeled tail: no more stages; counted drains 8 -> 4 -> 0
  VMW(8);
  BARRIER();
  COMPUTE(29);
  LGKM0();
  VMW(4);
  BARRIER();
  COMPUTE(30);
  LGKM0();
  VMW(0);
  BARRIER();
  COMPUTE(31);
  LGKM0();

  __syncthreads();  // staging LDS dead; reuse as allsums[4][1024] floats

  // ---- epilogue: relu+bias, Wf contraction, butterfly, cross-wn combine ----
  float* allsums = (float*)smem;

  const int hb = (int)(n0 & 511);    // h-offset of this tile
  const int e_idx = (int)(n0 >> 9);  // expert index (tile never crosses experts)

  float wfv[4][4];  // [t][j]
#pragma unroll
  for (int t = 0; t < 4; ++t)
#pragma unroll
    for (int j = 0; j < 4; ++j)
      wfv[t][j] = Wf[t * H_ + hb + wn * 64 + j * 16 + m16];
  float bias[4];
#pragma unroll
  for (int j = 0; j < 4; ++j) bias[j] = be[n0 + wn * 64 + j * 16 + m16];

  const int b0s = m16 & 1, b1s = (m16 >> 1) & 1, b2s = (m16 >> 2) & 1, b3s = (m16 >> 3) & 1;
#pragma unroll
  for (int i = 0; i < 8; ++i) {
    float eo[4][4];  // [j][reg]
#pragma unroll
    for (int j = 0; j < 4; ++j)
#pragma unroll
      for (int r = 0; r < 4; ++r) eo[j][r] = fmaxf(acc[i][j][r] + bias[j], 0.f);
    float p[16];  // slot s = reg*4 + t, partial over this lane's 4 cols
#pragma unroll
    for (int r = 0; r < 4; ++r)
#pragma unroll
      for (int t = 0; t < 4; ++t) {
        float v = 0.f;
#pragma unroll
        for (int j = 0; j < 4; ++j) v += eo[j][r] * wfv[t][j];
        p[r * 4 + t] = v;
      }
    // Compacting fold-exchange butterfly over the 16 m16-lanes:
    // after stage k, lane holds slots s with low (k+1) bits == m16's.
    float q8[8];
#pragma unroll
    for (int m = 0; m < 8; ++m) {
      float sent = b0s ? p[2 * m] : p[2 * m + 1];
      float recv = __shfl_xor(sent, 1, 64);
      q8[m] = (b0s ? p[2 * m + 1] : p[2 * m]) + recv;
    }
    float q4[4];
#pragma unroll
    for (int u = 0; u < 4; ++u) {
      float sent = b1s ? q8[2 * u] : q8[2 * u + 1];
      float recv = __shfl_xor(sent, 2, 64);
      q4[u] = (b1s ? q8[2 * u + 1] : q8[2 * u]) + recv;
    }
    float q2[2];
#pragma unroll
    for (int u = 0; u < 2; ++u) {
      float sent = b2s ? q4[2 * u] : q4[2 * u + 1];
      float recv = __shfl_xor(sent, 4, 64);
      q2[u] = (b2s ? q4[2 * u + 1] : q4[2 * u]) + recv;
    }
    float sent = b3s ? q2[0] : q2[1];
    float recv = __shfl_xor(sent, 8, 64);
    float v = (b3s ? q2[1] : q2[0]) + recv;  // slot == m16

    int row = wm * 128 + i * 16 + q * 4 + (m16 >> 2);  // reg_sel = m16>>2
    allsums[wn * 1024 + row * 4 + (m16 & 3)] = v;      // t_sel = m16&3
  }
  __syncthreads();

  // combine the 4 wn-quarters, apply gate, atomic-accumulate into out.
  {
    float2 s = *reinterpret_cast<float2*>(&allsums[0 * 1024 + tid * 2]);
    float2 x1 = *reinterpret_cast<float2*>(&allsums[1 * 1024 + tid * 2]);
    float2 x2 = *reinterpret_cast<float2*>(&allsums[2 * 1024 + tid * 2]);
    float2 x3 = *reinterpret_cast<float2*>(&allsums[3 * 1024 + tid * 2]);
    s.x += x1.x + x2.x + x3.x;
    s.y += x1.y + x2.y + x3.y;
#pragma unroll
    for (int oi = 0; oi < 2; ++oi) {
      int o = tid * 2 + oi;  // 1024 = 256 rows x 4 t
      int row = o >> 2, t = o & 3;
      float sv = oi ? s.y : s.x;
      size_t b = m0 + row;
      float gv = g[b * 64 + t * 16 + e_idx];
      atomicAdd(&out[(size_t)t * B_ + b], gv * sv);
    }
  }
}

extern "C" void kernel_launch(void* const* d_in, const int* in_sizes, int n_in,
                              void* d_out, int out_size, void* d_ws, size_t ws_size,
                              hipStream_t stream) {
  const float* x = (const float*)d_in[0];   // [B, I]
  const float* We = (const float*)d_in[1];  // [E, H, I]
  const float* be = (const float*)d_in[2];  // [E, H]
  const float* Wg = (const float*)d_in[3];  // [T, E, I]
  const float* bg = (const float*)d_in[4];  // [T, E]
  const float* Wf = (const float*)d_in[5];  // [T, H]
  const float* bf = (const float*)d_in[6];  // [T]
  float* out = (float*)d_out;               // [T, B, 1]

  // ws: xb (16.8MB) | wb (16.8MB) | wgb (0.13MB) | g (2.1MB)
  unsigned short* xb = (unsigned short*)d_ws;
  unsigned short* wb = xb + (size_t)B_ * K_;
  unsigned short* wgb = wb + (size_t)N_ * K_;
  float* g = (float*)(wgb + (size_t)64 * K_);

  // opt-in for 128 KiB dynamic LDS (host-side, not a stream op: capture-safe)
  hipFuncSetAttribute((const void*)moe_main_kernel,
                      hipFuncAttributeMaxDynamicSharedMemorySize, 131072);

  cvt3_kernel<<<(N4X + N4W + N4G + 255) / 256, 256, 0, stream>>>(x, We, Wg, bf, xb, wb, wgb, out);
  logits_softmax_kernel<<<B_ / 128, 256, 0, stream>>>(xb, wgb, bg, g);
  dim3 grid(B_ / 256, N_ / 256);  // x = mb (disjoint out rows among concurrent blocks)
  moe_main_kernel<<<grid, 512, 131072, stream>>>(xb, wb, be, Wf, g, out);
}

// Round 4
// 253.473 us; speedup vs baseline: 1.0235x; 1.0235x over previous
//
#include <hip/hip_runtime.h>
#include <hip/hip_bf16.h>
#include <stdint.h>

// MMoE: E=16 experts, T=4 tasks, H=512, I=1024, B=8192.
// out[t,b] = sum_e g[b,t,e] * (sum_h relu(x@We^T+be)[b,e,h] * Wf[t,h]) + bf[t]
//
// R17: register double-buffered fragments on the R16 4-ring. R14/R15/R16
// (three different barrier schedules) ALL measured 140-148 us, MfmaUtil
// 40-42%: window time 2700 cyc = LDS-read phase (~1150) + MFMA phase
// (~1244) SERIAL, because each window's MFMAs depend on that window's
// ds_reads (lgkm waits before first use; barrier-synced waves are in-phase,
// so no cross-wave anti-phasing). Fix: MFMAs at window t consume fragments
// read at window t-1 (already drained -> no wait); window t issues the 12
// ds_reads for tile t+1 into the OTHER register set, completing under the
// MFMA burst. LDS read time overlaps MFMA time.
// - Two named fragment sets (A/B suffixes, pair-unrolled loop — rule #20).
// - lgkmcnt(0) + sched_barrier(0) at window end (rule #18: register-only
//   MFMAs would hoist past the inline-asm drain).
// - Ledger: entry 8 outstanding (tiles t+1,t+2); VMW(4) -> tile t+1 done
//   (read this window); barrier -> all waves' t+1 stages done + all reads
//   of buf[(t+3)&3] drained (their LGKM0 was >=2 windows ago). Stage t+3.
//   Peeled tail t=28..31: VMW(4)/VMW(4)/VMW(0)/none.
// R13 invariant kept: blockIdx.x = mb -> disjoint out rows, no collision.

#define E_ 16
#define T_ 4
#define H_ 512
#define I_ 1024
#define B_ 8192
#define N_ (E_ * H_) /* 8192 */
#define K_ I_        /* 1024 */

typedef __bf16 bf16x8 __attribute__((ext_vector_type(8)));
typedef float f32x4 __attribute__((ext_vector_type(4)));

__device__ __forceinline__ unsigned short f2bf_rne(float f) {
  unsigned int b = __float_as_uint(f);
  b += 0x7fffu + ((b >> 16) & 1u);
  return (unsigned short)(b >> 16);
}

#define N4X (B_ * K_ / 4) /* 2097152 */
#define N4W (N_ * K_ / 4) /* 2097152 */
#define N4G (64 * K_ / 4) /* 16384 */

// merged fp32 -> bf16 (RNE) for x | We | Wg, float4 in / ushort4 out.
// First T_*B_ threads also initialize out[t*B+b] = bf[t] (atomic-accumulated
// by moe_main later; harness re-poisons out before every launch).
__global__ __launch_bounds__(256) void cvt3_kernel(const float* __restrict__ x,
                                                   const float* __restrict__ We,
                                                   const float* __restrict__ Wg,
                                                   const float* __restrict__ bfv,
                                                   unsigned short* __restrict__ xb,
                                                   unsigned short* __restrict__ wb,
                                                   unsigned short* __restrict__ wgb,
                                                   float* __restrict__ out) {
  int i = blockIdx.x * 256 + threadIdx.x;
  if (i < T_ * B_) out[i] = bfv[i >> 13];  // t = i / 8192
  const float* src;
  unsigned short* dst;
  int j;
  if (i < N4X) {
    src = x; dst = xb; j = i;
  } else if (i < N4X + N4W) {
    src = We; dst = wb; j = i - N4X;
  } else if (i < N4X + N4W + N4G) {
    src = Wg; dst = wgb; j = i - (N4X + N4W);
  } else {
    return;
  }
  float4 v = reinterpret_cast<const float4*>(src)[j];
  ushort4 o;
  o.x = f2bf_rne(v.x);
  o.y = f2bf_rne(v.y);
  o.z = f2bf_rne(v.z);
  o.w = f2bf_rne(v.w);
  reinterpret_cast<ushort4*>(dst)[j] = o;
}

__device__ __forceinline__ void gld_lds16(const void* gp, void* lp) {
  __builtin_amdgcn_global_load_lds((const __attribute__((address_space(1))) void*)gp,
                                   (__attribute__((address_space(3))) void*)lp, 16, 0, 0);
}

// logits L[b][te] = x[b,:]@Wg[te,:] + bg[te] via bf16 MFMA (Wg [T][E][I] is
// already B^T [64][1024]), then softmax over e (= the 16 m16-lanes) in
// registers -> g[b][64]. Tile: M=128, N=64, BK=32; 4 waves x 32 rows each.
__global__ __launch_bounds__(256) void logits_softmax_kernel(
    const unsigned short* __restrict__ A,    // x bf16 [B_][K_]
    const unsigned short* __restrict__ Bm,   // Wg bf16 [64][K_]
    const float* __restrict__ bg,            // [64]
    float* __restrict__ g)                   // [B_][64]
{
  __shared__ struct {
    unsigned short A[128 * 32];  // 8 KB
    unsigned short B[64 * 32];   // 4 KB
  } st;

  const int tid = threadIdx.x;
  const int w = tid >> 6, l = tid & 63;
  const int m16 = l & 15, q = l >> 4;
  const size_t m0 = (size_t)blockIdx.x * 128;

  // A staging: rows w*32..w*32+31, 2 chunks/thread
  const int r0s = (w * 2 + 0) * 16 + (l >> 2);
  const int r1s = (w * 2 + 1) * 16 + (l >> 2);
  const int slot = l & 3;
  const int c0 = slot ^ ((r0s >> 1) & 3);
  const int c1 = slot ^ ((r1s >> 1) & 3);
  const size_t offA0 = (m0 + r0s) * K_ + c0 * 8;
  const size_t offA1 = (m0 + r1s) * K_ + c1 * 8;
  const int l0 = (w * 2 + 0) * 512;
  const int l1 = (w * 2 + 1) * 512;
  // B staging: 64 rows, 1 chunk/thread; wave w covers rows w*16..w*16+15
  const int rBs = w * 16 + (l >> 2);
  const int cB = slot ^ ((rBs >> 1) & 3);
  const size_t offB = (size_t)rBs * K_ + cB * 8;
  const int lB = w * 512;

  const int arow = w * 32 + m16;
  const int sA = q ^ ((arow >> 1) & 3);
  const int sB = q ^ ((m16 >> 1) & 3);

  f32x4 acc[2][4] = {};

  for (int k0 = 0; k0 < K_; k0 += 32) {
    __syncthreads();
    gld_lds16(A + offA0 + k0, st.A + l0);
    gld_lds16(A + offA1 + k0, st.A + l1);
    gld_lds16(Bm + offB + k0, st.B + lB);
    __syncthreads();
    bf16x8 af[2], bfr[4];
#pragma unroll
    for (int i = 0; i < 2; ++i)
      af[i] = *reinterpret_cast<const bf16x8*>(st.A + (arow + i * 16) * 32 + sA * 8);
#pragma unroll
    for (int j = 0; j < 4; ++j)
      bfr[j] = *reinterpret_cast<const bf16x8*>(st.B + (j * 16 + m16) * 32 + sB * 8);
#pragma unroll
    for (int i = 0; i < 2; ++i)
#pragma unroll
      for (int j = 0; j < 4; ++j)
        acc[i][j] = __builtin_amdgcn_mfma_f32_16x16x32_bf16(af[i], bfr[j], acc[i][j], 0, 0, 0);
  }

  // acc[i][j][r] = L[row = w*32+16i+4q+r][te = j*16+m16]; t = j, e = m16.
  float bgv[4];
#pragma unroll
  for (int j = 0; j < 4; ++j) bgv[j] = bg[j * 16 + m16];

#pragma unroll
  for (int i = 0; i < 2; ++i) {
    float lg[4][4];  // [r][j]
#pragma unroll
    for (int j = 0; j < 4; ++j)
#pragma unroll
      for (int r = 0; r < 4; ++r) lg[r][j] = acc[i][j][r] + bgv[j];
#pragma unroll
    for (int r = 0; r < 4; ++r) {
#pragma unroll
      for (int j = 0; j < 4; ++j) {
        float m = lg[r][j];
#pragma unroll
        for (int mask = 1; mask < 16; mask <<= 1) m = fmaxf(m, __shfl_xor(m, mask, 64));
        float ex = __expf(lg[r][j] - m);
        float s = ex;
#pragma unroll
        for (int mask = 1; mask < 16; mask <<= 1) s += __shfl_xor(s, mask, 64);
        size_t b = m0 + w * 32 + i * 16 + q * 4 + r;
        g[b * 64 + j * 16 + m16] = ex / s;
      }
    }
  }
}

// ------- 256^2 single-barrier 4-ring + register-double-buffered main -------

extern __shared__ char smem[];  // 131072 B: ring buf b at b*32768; A +0, B +16384

#define BARRIER()                          \
  do {                                     \
    asm volatile("" ::: "memory");         \
    __builtin_amdgcn_s_barrier();          \
    asm volatile("" ::: "memory");         \
  } while (0)
#define VMW(n) asm volatile("s_waitcnt vmcnt(" #n ")" ::: "memory")
#define LGKM0() asm volatile("s_waitcnt lgkmcnt(0)" ::: "memory")
#define SCHED0() __builtin_amdgcn_sched_barrier(0)

// stage K-tile t (256 rows x 32 k of A and B) into ring buf t&3.
// Per wave: 2 gld for A (16 rows x 64 B each) + 2 for B. LDS dest is
// wave-uniform (HW adds lane*16); global src carries the swizzle
// chunk c = (l&3) ^ ((l>>3)&3).
#define STAGE4(t_)                                                             \
  do {                                                                         \
    const int bb_ = ((t_) & 3) * 32768;                                        \
    const int ko_ = (t_) * 32;                                                 \
    gld_lds16(A + baseAg + ko_, smem + bb_ + ldsW);                            \
    gld_lds16(A + baseAg + 16 * K_ + ko_, smem + bb_ + ldsW + 1024);           \
    gld_lds16(Bm + baseBg + ko_, smem + bb_ + 16384 + ldsW);                   \
    gld_lds16(Bm + baseBg + 16 * K_ + ko_, smem + bb_ + 16384 + ldsW + 1024);  \
  } while (0)

// read the 12 fragments of K-tile t into register set S (afS/bfrS).
// No consumer this window -> no lgkm wait before this window's MFMAs.
#define READF(S, t_)                                                                      \
  do {                                                                                    \
    const int bb_ = ((t_) & 3) * 32768;                                                   \
    _Pragma("unroll") for (int i = 0; i < 8; ++i) af##S[i] =                              \
        *reinterpret_cast<const bf16x8*>(smem + bb_ + baseA_rd + i * 1024 + sl16);        \
    _Pragma("unroll") for (int j = 0; j < 4; ++j) bfr##S[j] =                             \
        *reinterpret_cast<const bf16x8*>(smem + bb_ + 16384 + baseB_rd + j * 1024 + sl16);\
  } while (0)

// 32 MFMAs on register set S (fragments drained LAST window -> zero wait).
#define MFMA32(S)                                                                         \
  do {                                                                                    \
    __builtin_amdgcn_s_setprio(1);                                                        \
    _Pragma("unroll") for (int i = 0; i < 8; ++i)                                         \
        _Pragma("unroll") for (int j = 0; j < 4; ++j)                                     \
            acc[i][j] = __builtin_amdgcn_mfma_f32_16x16x32_bf16(af##S[i], bfr##S[j],      \
                                                                acc[i][j], 0, 0, 0);      \
    __builtin_amdgcn_s_setprio(0);                                                        \
  } while (0)

__global__ __launch_bounds__(512, 2) void moe_main_kernel(
    const unsigned short* __restrict__ A,   // x bf16 [B_][K_]
    const unsigned short* __restrict__ Bm,  // We bf16 [N_][K_]
    const float* __restrict__ be,           // [E_*H_] flat == indexed by n
    const float* __restrict__ Wf,           // [T_][H_]
    const float* __restrict__ g,            // [B_][64] (t*16+e)
    float* __restrict__ out)                // [T_][B_] (pre-init to bf[t])
{
  const int tid = threadIdx.x;
  const int w = tid >> 6, l = tid & 63;
  const int wm = w >> 2, wn = w & 3;  // 2 M-waves x 4 N-waves; wave tile 128x64
  const int m16 = l & 15, q = l >> 4;
  const int mb = blockIdx.x, nb = blockIdx.y;  // x=mb: decorrelate atomics (R13)
  const size_t m0 = (size_t)mb * 256, n0 = (size_t)nb * 256;

  // global staging bases (elements); lane covers row w*32 + (l>>2) (+16 for
  // the 2nd gld), chunk c8 = ((l&3) ^ ((l>>3)&3)) * 8.
  const int c8 = (((l & 3) ^ ((l >> 3) & 3)) * 8);
  const size_t baseAg = (m0 + w * 32 + (l >> 2)) * K_ + c8;
  const size_t baseBg = (n0 + w * 32 + (l >> 2)) * K_ + c8;
  const int ldsW = w * 2048;  // (w*32 rows) * 64 B

  // ds_read addressing: row r at byte r*64; 16B slot q ^ ((r>>1)&3); for all
  // fragment rows (r>>1)&3 == (m16>>1)&3 (row-base multiples of 16 drop out).
  const int sl16 = (q ^ ((m16 >> 1) & 3)) * 16;
  const int baseA_rd = (wm * 128 + m16) * 64;
  const int baseB_rd = (wn * 64 + m16) * 64;

  f32x4 acc[8][4] = {};
  bf16x8 afA[8], bfrA[4], afB[8], bfrB[4];

  // prologue: prime ring with tiles 0,1,2; load tile-0 fragments into set A.
  STAGE4(0);
  STAGE4(1);
  STAGE4(2);
  VMW(8);   // tile 0 staged (own); barrier makes it collective
  BARRIER();
  READF(A, 0);
  LGKM0();
  SCHED0();

  // window t (steady, entry invariant: 8 outstanding = tiles t+1,t+2; set
  // 'cur' holds tile-t fragments, drained):
  //   VMW(4)  -> own tile-t+1 stages done
  //   BARRIER -> ALL waves' tile-t+1 stages done; all reads of buf[(t+3)&3]
  //              drained (their LGKM0 was at window t-2)
  //   STAGE4(t+3) ; READF(nxt, t+1) ; MFMA32(cur) ; LGKM0 ; sched_barrier
  // Pair-unrolled so the two fragment sets are statically named (rule #20).
#pragma unroll 1
  for (int t = 0; t < 28; t += 2) {
    VMW(4);
    BARRIER();
    STAGE4(t + 3);
    READF(B, t + 1);
    MFMA32(A);
    LGKM0();
    SCHED0();
    VMW(4);
    BARRIER();
    STAGE4(t + 4);
    READF(A, t + 2);
    MFMA32(B);
    LGKM0();
    SCHED0();
  }
  // t=28: stage 31, read 29
  VMW(4);
  BARRIER();
  STAGE4(31);
  READF(B, 29);
  MFMA32(A);
  LGKM0();
  SCHED0();
  // t=29: read 30 (VMW(4): tile 30 done, tile 31 in flight)
  VMW(4);
  BARRIER();
  READF(A, 30);
  MFMA32(B);
  LGKM0();
  SCHED0();
  // t=30: read 31 (VMW(0): tile 31 done)
  VMW(0);
  BARRIER();
  READF(B, 31);
  MFMA32(A);
  LGKM0();
  SCHED0();
  // t=31: compute only
  MFMA32(B);

  __syncthreads();  // staging LDS dead; reuse as allsums[4][1024] floats

  // ---- epilogue: relu+bias, Wf contraction, butterfly, cross-wn combine ----
  float* allsums = (float*)smem;

  const int hb = (int)(n0 & 511);    // h-offset of this tile
  const int e_idx = (int)(n0 >> 9);  // expert index (tile never crosses experts)

  float wfv[4][4];  // [t][j]
#pragma unroll
  for (int t = 0; t < 4; ++t)
#pragma unroll
    for (int j = 0; j < 4; ++j)
      wfv[t][j] = Wf[t * H_ + hb + wn * 64 + j * 16 + m16];
  float bias[4];
#pragma unroll
  for (int j = 0; j < 4; ++j) bias[j] = be[n0 + wn * 64 + j * 16 + m16];

  const int b0s = m16 & 1, b1s = (m16 >> 1) & 1, b2s = (m16 >> 2) & 1, b3s = (m16 >> 3) & 1;
#pragma unroll
  for (int i = 0; i < 8; ++i) {
    float eo[4][4];  // [j][reg]
#pragma unroll
    for (int j = 0; j < 4; ++j)
#pragma unroll
      for (int r = 0; r < 4; ++r) eo[j][r] = fmaxf(acc[i][j][r] + bias[j], 0.f);
    float p[16];  // slot s = reg*4 + t, partial over this lane's 4 cols
#pragma unroll
    for (int r = 0; r < 4; ++r)
#pragma unroll
      for (int t = 0; t < 4; ++t) {
        float v = 0.f;
#pragma unroll
        for (int j = 0; j < 4; ++j) v += eo[j][r] * wfv[t][j];
        p[r * 4 + t] = v;
      }
    // Compacting fold-exchange butterfly over the 16 m16-lanes:
    // after stage k, lane holds slots s with low (k+1) bits == m16's.
    float q8[8];
#pragma unroll
    for (int m = 0; m < 8; ++m) {
      float sent = b0s ? p[2 * m] : p[2 * m + 1];
      float recv = __shfl_xor(sent, 1, 64);
      q8[m] = (b0s ? p[2 * m + 1] : p[2 * m]) + recv;
    }
    float q4[4];
#pragma unroll
    for (int u = 0; u < 4; ++u) {
      float sent = b1s ? q8[2 * u] : q8[2 * u + 1];
      float recv = __shfl_xor(sent, 2, 64);
      q4[u] = (b1s ? q8[2 * u + 1] : q8[2 * u]) + recv;
    }
    float q2[2];
#pragma unroll
    for (int u = 0; u < 2; ++u) {
      float sent = b2s ? q4[2 * u] : q4[2 * u + 1];
      float recv = __shfl_xor(sent, 4, 64);
      q2[u] = (b2s ? q4[2 * u + 1] : q4[2 * u]) + recv;
    }
    float sent = b3s ? q2[0] : q2[1];
    float recv = __shfl_xor(sent, 8, 64);
    float v = (b3s ? q2[1] : q2[0]) + recv;  // slot == m16

    int row = wm * 128 + i * 16 + q * 4 + (m16 >> 2);  // reg_sel = m16>>2
    allsums[wn * 1024 + row * 4 + (m16 & 3)] = v;      // t_sel = m16&3
  }
  __syncthreads();

  // combine the 4 wn-quarters, apply gate, atomic-accumulate into out.
  {
    float2 s = *reinterpret_cast<float2*>(&allsums[0 * 1024 + tid * 2]);
    float2 x1 = *reinterpret_cast<float2*>(&allsums[1 * 1024 + tid * 2]);
    float2 x2 = *reinterpret_cast<float2*>(&allsums[2 * 1024 + tid * 2]);
    float2 x3 = *reinterpret_cast<float2*>(&allsums[3 * 1024 + tid * 2]);
    s.x += x1.x + x2.x + x3.x;
    s.y += x1.y + x2.y + x3.y;
#pragma unroll
    for (int oi = 0; oi < 2; ++oi) {
      int o = tid * 2 + oi;  // 1024 = 256 rows x 4 t
      int row = o >> 2, t = o & 3;
      float sv = oi ? s.y : s.x;
      size_t b = m0 + row;
      float gv = g[b * 64 + t * 16 + e_idx];
      atomicAdd(&out[(size_t)t * B_ + b], gv * sv);
    }
  }
}

extern "C" void kernel_launch(void* const* d_in, const int* in_sizes, int n_in,
                              void* d_out, int out_size, void* d_ws, size_t ws_size,
                              hipStream_t stream) {
  const float* x = (const float*)d_in[0];   // [B, I]
  const float* We = (const float*)d_in[1];  // [E, H, I]
  const float* be = (const float*)d_in[2];  // [E, H]
  const float* Wg = (const float*)d_in[3];  // [T, E, I]
  const float* bg = (const float*)d_in[4];  // [T, E]
  const float* Wf = (const float*)d_in[5];  // [T, H]
  const float* bf = (const float*)d_in[6];  // [T]
  float* out = (float*)d_out;               // [T, B, 1]

  // ws: xb (16.8MB) | wb (16.8MB) | wgb (0.13MB) | g (2.1MB)
  unsigned short* xb = (unsigned short*)d_ws;
  unsigned short* wb = xb + (size_t)B_ * K_;
  unsigned short* wgb = wb + (size_t)N_ * K_;
  float* g = (float*)(wgb + (size_t)64 * K_);

  // opt-in for 128 KiB dynamic LDS (host-side, not a stream op: capture-safe)
  hipFuncSetAttribute((const void*)moe_main_kernel,
                      hipFuncAttributeMaxDynamicSharedMemorySize, 131072);

  cvt3_kernel<<<(N4X + N4W + N4G + 255) / 256, 256, 0, stream>>>(x, We, Wg, bf, xb, wb, wgb, out);
  logits_softmax_kernel<<<B_ / 128, 256, 0, stream>>>(xb, wgb, bg, g);
  dim3 grid(B_ / 256, N_ / 256);  // x = mb (disjoint out rows among concurrent blocks)
  moe_main_kernel<<<grid, 512, 131072, stream>>>(xb, wb, be, Wf, g, out);
}

// Round 5
// 252.573 us; speedup vs baseline: 1.0271x; 1.0036x over previous
//
#include <hip/hip_runtime.h>
#include <hip/hip_bf16.h>
#include <stdint.h>

// MMoE: E=16 experts, T=4 tasks, H=512, I=1024, B=8192.
// out[t,b] = sum_e g[b,t,e] * (sum_h relu(x@We^T+be)[b,e,h] * Wf[t,h]) + bf[t]
//
// R18: COUNTED lgkmcnt on the R17 ring-4 + reg-dbuf structure.
// R14..R17 (four schedules) all measured 140-148 us, MfmaUtil 40-42%, and
// the window time 2700 cyc = LDS-pipe time (1400: 96 ds_read_b128 + 32 KB
// gld writes) + MFMA-pipe time (1242) EXACTLY SUMMED -> zero overlap.
// Root cause: R17's per-window s_waitcnt lgkmcnt(0) drained all 12 reads
// before each barrier, so the LDS pipe only worked while the matrix pipe
// was idle. Fix = the lgkm analog of "never vmcnt(0) in the loop": reads
// R_t (issued window t for tile t+1) stay IN FLIGHT through window t's
// MFMA burst and the barrier; safety via counted lgkmcnt(12) + DS in-order
// completion:
//   - entry guard: lgkmcnt(12) => outstanding <= R_{t-1} => R_{t-2} fully
//     retired => buf[(t-1)&3] read-free => STAGE4(t+3) safe. (If any
//     R_{t-2} pending, all 12 R_{t-1} are newer/pending too => >12 => wait
//     holds. Airtight given DS in-order.)
//   - operand guard: after READF issues R_t, lgkmcnt(12) => R_{t-1} done
//     => current fragment set valid; sched_barrier(0) pins MFMAs below
//     (rule #18: "memory" clobber does not order register-only MFMAs).
// vmcnt stays counted at 4 (2 tiles in flight); lgkm/vm drain to 0 only in
// the peeled tail. R13 invariant kept: blockIdx.x = mb -> disjoint out rows.

#define E_ 16
#define T_ 4
#define H_ 512
#define I_ 1024
#define B_ 8192
#define N_ (E_ * H_) /* 8192 */
#define K_ I_        /* 1024 */

typedef __bf16 bf16x8 __attribute__((ext_vector_type(8)));
typedef float f32x4 __attribute__((ext_vector_type(4)));

__device__ __forceinline__ unsigned short f2bf_rne(float f) {
  unsigned int b = __float_as_uint(f);
  b += 0x7fffu + ((b >> 16) & 1u);
  return (unsigned short)(b >> 16);
}

#define N4X (B_ * K_ / 4) /* 2097152 */
#define N4W (N_ * K_ / 4) /* 2097152 */
#define N4G (64 * K_ / 4) /* 16384 */

// merged fp32 -> bf16 (RNE) for x | We | Wg, float4 in / ushort4 out.
// First T_*B_ threads also initialize out[t*B+b] = bf[t] (atomic-accumulated
// by moe_main later; harness re-poisons out before every launch).
__global__ __launch_bounds__(256) void cvt3_kernel(const float* __restrict__ x,
                                                   const float* __restrict__ We,
                                                   const float* __restrict__ Wg,
                                                   const float* __restrict__ bfv,
                                                   unsigned short* __restrict__ xb,
                                                   unsigned short* __restrict__ wb,
                                                   unsigned short* __restrict__ wgb,
                                                   float* __restrict__ out) {
  int i = blockIdx.x * 256 + threadIdx.x;
  if (i < T_ * B_) out[i] = bfv[i >> 13];  // t = i / 8192
  const float* src;
  unsigned short* dst;
  int j;
  if (i < N4X) {
    src = x; dst = xb; j = i;
  } else if (i < N4X + N4W) {
    src = We; dst = wb; j = i - N4X;
  } else if (i < N4X + N4W + N4G) {
    src = Wg; dst = wgb; j = i - (N4X + N4W);
  } else {
    return;
  }
  float4 v = reinterpret_cast<const float4*>(src)[j];
  ushort4 o;
  o.x = f2bf_rne(v.x);
  o.y = f2bf_rne(v.y);
  o.z = f2bf_rne(v.z);
  o.w = f2bf_rne(v.w);
  reinterpret_cast<ushort4*>(dst)[j] = o;
}

__device__ __forceinline__ void gld_lds16(const void* gp, void* lp) {
  __builtin_amdgcn_global_load_lds((const __attribute__((address_space(1))) void*)gp,
                                   (__attribute__((address_space(3))) void*)lp, 16, 0, 0);
}

// logits L[b][te] = x[b,:]@Wg[te,:] + bg[te] via bf16 MFMA (Wg [T][E][I] is
// already B^T [64][1024]), then softmax over e (= the 16 m16-lanes) in
// registers -> g[b][64]. Tile: M=128, N=64, BK=32; 4 waves x 32 rows each.
__global__ __launch_bounds__(256) void logits_softmax_kernel(
    const unsigned short* __restrict__ A,    // x bf16 [B_][K_]
    const unsigned short* __restrict__ Bm,   // Wg bf16 [64][K_]
    const float* __restrict__ bg,            // [64]
    float* __restrict__ g)                   // [B_][64]
{
  __shared__ struct {
    unsigned short A[128 * 32];  // 8 KB
    unsigned short B[64 * 32];   // 4 KB
  } st;

  const int tid = threadIdx.x;
  const int w = tid >> 6, l = tid & 63;
  const int m16 = l & 15, q = l >> 4;
  const size_t m0 = (size_t)blockIdx.x * 128;

  // A staging: rows w*32..w*32+31, 2 chunks/thread
  const int r0s = (w * 2 + 0) * 16 + (l >> 2);
  const int r1s = (w * 2 + 1) * 16 + (l >> 2);
  const int slot = l & 3;
  const int c0 = slot ^ ((r0s >> 1) & 3);
  const int c1 = slot ^ ((r1s >> 1) & 3);
  const size_t offA0 = (m0 + r0s) * K_ + c0 * 8;
  const size_t offA1 = (m0 + r1s) * K_ + c1 * 8;
  const int l0 = (w * 2 + 0) * 512;
  const int l1 = (w * 2 + 1) * 512;
  // B staging: 64 rows, 1 chunk/thread; wave w covers rows w*16..w*16+15
  const int rBs = w * 16 + (l >> 2);
  const int cB = slot ^ ((rBs >> 1) & 3);
  const size_t offB = (size_t)rBs * K_ + cB * 8;
  const int lB = w * 512;

  const int arow = w * 32 + m16;
  const int sA = q ^ ((arow >> 1) & 3);
  const int sB = q ^ ((m16 >> 1) & 3);

  f32x4 acc[2][4] = {};

  for (int k0 = 0; k0 < K_; k0 += 32) {
    __syncthreads();
    gld_lds16(A + offA0 + k0, st.A + l0);
    gld_lds16(A + offA1 + k0, st.A + l1);
    gld_lds16(Bm + offB + k0, st.B + lB);
    __syncthreads();
    bf16x8 af[2], bfr[4];
#pragma unroll
    for (int i = 0; i < 2; ++i)
      af[i] = *reinterpret_cast<const bf16x8*>(st.A + (arow + i * 16) * 32 + sA * 8);
#pragma unroll
    for (int j = 0; j < 4; ++j)
      bfr[j] = *reinterpret_cast<const bf16x8*>(st.B + (j * 16 + m16) * 32 + sB * 8);
#pragma unroll
    for (int i = 0; i < 2; ++i)
#pragma unroll
      for (int j = 0; j < 4; ++j)
        acc[i][j] = __builtin_amdgcn_mfma_f32_16x16x32_bf16(af[i], bfr[j], acc[i][j], 0, 0, 0);
  }

  // acc[i][j][r] = L[row = w*32+16i+4q+r][te = j*16+m16]; t = j, e = m16.
  float bgv[4];
#pragma unroll
  for (int j = 0; j < 4; ++j) bgv[j] = bg[j * 16 + m16];

#pragma unroll
  for (int i = 0; i < 2; ++i) {
    float lg[4][4];  // [r][j]
#pragma unroll
    for (int j = 0; j < 4; ++j)
#pragma unroll
      for (int r = 0; r < 4; ++r) lg[r][j] = acc[i][j][r] + bgv[j];
#pragma unroll
    for (int r = 0; r < 4; ++r) {
#pragma unroll
      for (int j = 0; j < 4; ++j) {
        float m = lg[r][j];
#pragma unroll
        for (int mask = 1; mask < 16; mask <<= 1) m = fmaxf(m, __shfl_xor(m, mask, 64));
        float ex = __expf(lg[r][j] - m);
        float s = ex;
#pragma unroll
        for (int mask = 1; mask < 16; mask <<= 1) s += __shfl_xor(s, mask, 64);
        size_t b = m0 + w * 32 + i * 16 + q * 4 + r;
        g[b * 64 + j * 16 + m16] = ex / s;
      }
    }
  }
}

// -- 256^2 single-barrier 4-ring, reg-dbuf, COUNTED-lgkm main kernel --

extern __shared__ char smem[];  // 131072 B: ring buf b at b*32768; A +0, B +16384

#define BARRIER()                          \
  do {                                     \
    asm volatile("" ::: "memory");         \
    __builtin_amdgcn_s_barrier();          \
    asm volatile("" ::: "memory");         \
  } while (0)
#define VMW(n) asm volatile("s_waitcnt vmcnt(" #n ")" ::: "memory")
#define LGKM(n) asm volatile("s_waitcnt lgkmcnt(" #n ")" ::: "memory")
#define SCHED0() __builtin_amdgcn_sched_barrier(0)

// stage K-tile t (256 rows x 32 k of A and B) into ring buf t&3.
// Per wave: 2 gld for A (16 rows x 64 B each) + 2 for B. LDS dest is
// wave-uniform (HW adds lane*16); global src carries the swizzle
// chunk c = (l&3) ^ ((l>>3)&3).
#define STAGE4(t_)                                                             \
  do {                                                                         \
    const int bb_ = ((t_) & 3) * 32768;                                        \
    const int ko_ = (t_) * 32;                                                 \
    gld_lds16(A + baseAg + ko_, smem + bb_ + ldsW);                            \
    gld_lds16(A + baseAg + 16 * K_ + ko_, smem + bb_ + ldsW + 1024);           \
    gld_lds16(Bm + baseBg + ko_, smem + bb_ + 16384 + ldsW);                   \
    gld_lds16(Bm + baseBg + 16 * K_ + ko_, smem + bb_ + 16384 + ldsW + 1024);  \
  } while (0)

// read the 12 fragments of K-tile t into register set S (afS/bfrS).
// These reads stay outstanding through this window's MFMA burst (counted
// lgkm) — consumed only next window.
#define READF(S, t_)                                                                      \
  do {                                                                                    \
    const int bb_ = ((t_) & 3) * 32768;                                                   \
    _Pragma("unroll") for (int i = 0; i < 8; ++i) af##S[i] =                              \
        *reinterpret_cast<const bf16x8*>(smem + bb_ + baseA_rd + i * 1024 + sl16);        \
    _Pragma("unroll") for (int j = 0; j < 4; ++j) bfr##S[j] =                             \
        *reinterpret_cast<const bf16x8*>(smem + bb_ + 16384 + baseB_rd + j * 1024 + sl16);\
  } while (0)

// 32 MFMAs on register set S; trailing sched_barrier pins them in-window.
#define MFMA32(S)                                                                         \
  do {                                                                                    \
    __builtin_amdgcn_s_setprio(1);                                                        \
    _Pragma("unroll") for (int i = 0; i < 8; ++i)                                         \
        _Pragma("unroll") for (int j = 0; j < 4; ++j)                                     \
            acc[i][j] = __builtin_amdgcn_mfma_f32_16x16x32_bf16(af##S[i], bfr##S[j],      \
                                                                acc[i][j], 0, 0, 0);      \
    __builtin_amdgcn_s_setprio(0);                                                        \
    SCHED0();                                                                             \
  } while (0)

__global__ __launch_bounds__(512, 2) void moe_main_kernel(
    const unsigned short* __restrict__ A,   // x bf16 [B_][K_]
    const unsigned short* __restrict__ Bm,  // We bf16 [N_][K_]
    const float* __restrict__ be,           // [E_*H_] flat == indexed by n
    const float* __restrict__ Wf,           // [T_][H_]
    const float* __restrict__ g,            // [B_][64] (t*16+e)
    float* __restrict__ out)                // [T_][B_] (pre-init to bf[t])
{
  const int tid = threadIdx.x;
  const int w = tid >> 6, l = tid & 63;
  const int wm = w >> 2, wn = w & 3;  // 2 M-waves x 4 N-waves; wave tile 128x64
  const int m16 = l & 15, q = l >> 4;
  const int mb = blockIdx.x, nb = blockIdx.y;  // x=mb: decorrelate atomics (R13)
  const size_t m0 = (size_t)mb * 256, n0 = (size_t)nb * 256;

  // global staging bases (elements); lane covers row w*32 + (l>>2) (+16 for
  // the 2nd gld), chunk c8 = ((l&3) ^ ((l>>3)&3)) * 8.
  const int c8 = (((l & 3) ^ ((l >> 3) & 3)) * 8);
  const size_t baseAg = (m0 + w * 32 + (l >> 2)) * K_ + c8;
  const size_t baseBg = (n0 + w * 32 + (l >> 2)) * K_ + c8;
  const int ldsW = w * 2048;  // (w*32 rows) * 64 B

  // ds_read addressing: row r at byte r*64; 16B slot q ^ ((r>>1)&3); for all
  // fragment rows (r>>1)&3 == (m16>>1)&3 (row-base multiples of 16 drop out).
  const int sl16 = (q ^ ((m16 >> 1) & 3)) * 16;
  const int baseA_rd = (wm * 128 + m16) * 64;
  const int baseB_rd = (wn * 64 + m16) * 64;

  f32x4 acc[8][4] = {};
  bf16x8 afA[8], bfrA[4], afB[8], bfrB[4];

  // prologue: prime ring with tiles 0,1,2; issue R_{-1} (tile-0 fragments)
  // into set A and leave it IN FLIGHT (no drain).
  STAGE4(0);
  STAGE4(1);
  STAGE4(2);
  VMW(8);   // tile 0 staged (own); barrier makes it collective
  BARRIER();
  READF(A, 0);

  // window t (steady, entry: VM outstanding = 8 = stages t+1,t+2; DS
  // outstanding <= R_{t-1}; 'cur' set will hold tile-t frags once R_{t-1}
  // retires):
  //   VMW(4)   -> own tile-t+1 stages done
  //   BARRIER  -> collective
  //   LGKM(12) -> R_{t-2} retired (ring: buf[(t-1)&3] read-free)
  //   STAGE4(t+3) into buf[(t-1)&3]
  //   READF(nxt, t+1)  [R_t issues; drains under the MFMA burst]
  //   LGKM(12); SCHED0 -> R_{t-1} retired; cur-set operands valid
  //   MFMA32(cur)
  // Pair-unrolled so the two fragment sets are statically named (rule #20).
#pragma unroll 1
  for (int t = 0; t < 28; t += 2) {
    VMW(4);
    BARRIER();
    LGKM(12);
    STAGE4(t + 3);
    READF(B, t + 1);
    LGKM(12);
    SCHED0();
    MFMA32(A);

    VMW(4);
    BARRIER();
    LGKM(12);
    STAGE4(t + 4);
    READF(A, t + 2);
    LGKM(12);
    SCHED0();
    MFMA32(B);
  }
  // t=28: last stage (tile 31)
  VMW(4);
  BARRIER();
  LGKM(12);
  STAGE4(31);
  READF(B, 29);
  LGKM(12);
  SCHED0();
  MFMA32(A);
  // t=29: no stage; VMW(4) -> stage(30) done
  VMW(4);
  BARRIER();
  READF(A, 30);
  LGKM(12);
  SCHED0();
  MFMA32(B);
  // t=30: VMW(0) -> stage(31) done
  VMW(0);
  BARRIER();
  READF(B, 31);
  LGKM(12);
  SCHED0();
  MFMA32(A);
  // t=31: compute only; drain R_31
  LGKM(0);
  SCHED0();
  MFMA32(B);

  __syncthreads();  // staging LDS dead; reuse as allsums[4][1024] floats

  // ---- epilogue: relu+bias, Wf contraction, butterfly, cross-wn combine ----
  float* allsums = (float*)smem;

  const int hb = (int)(n0 & 511);    // h-offset of this tile
  const int e_idx = (int)(n0 >> 9);  // expert index (tile never crosses experts)

  float wfv[4][4];  // [t][j]
#pragma unroll
  for (int t = 0; t < 4; ++t)
#pragma unroll
    for (int j = 0; j < 4; ++j)
      wfv[t][j] = Wf[t * H_ + hb + wn * 64 + j * 16 + m16];
  float bias[4];
#pragma unroll
  for (int j = 0; j < 4; ++j) bias[j] = be[n0 + wn * 64 + j * 16 + m16];

  const int b0s = m16 & 1, b1s = (m16 >> 1) & 1, b2s = (m16 >> 2) & 1, b3s = (m16 >> 3) & 1;
#pragma unroll
  for (int i = 0; i < 8; ++i) {
    float eo[4][4];  // [j][reg]
#pragma unroll
    for (int j = 0; j < 4; ++j)
#pragma unroll
      for (int r = 0; r < 4; ++r) eo[j][r] = fmaxf(acc[i][j][r] + bias[j], 0.f);
    float p[16];  // slot s = reg*4 + t, partial over this lane's 4 cols
#pragma unroll
    for (int r = 0; r < 4; ++r)
#pragma unroll
      for (int t = 0; t < 4; ++t) {
        float v = 0.f;
#pragma unroll
        for (int j = 0; j < 4; ++j) v += eo[j][r] * wfv[t][j];
        p[r * 4 + t] = v;
      }
    // Compacting fold-exchange butterfly over the 16 m16-lanes:
    // after stage k, lane holds slots s with low (k+1) bits == m16's.
    float q8[8];
#pragma unroll
    for (int m = 0; m < 8; ++m) {
      float sent = b0s ? p[2 * m] : p[2 * m + 1];
      float recv = __shfl_xor(sent, 1, 64);
      q8[m] = (b0s ? p[2 * m + 1] : p[2 * m]) + recv;
    }
    float q4[4];
#pragma unroll
    for (int u = 0; u < 4; ++u) {
      float sent = b1s ? q8[2 * u] : q8[2 * u + 1];
      float recv = __shfl_xor(sent, 2, 64);
      q4[u] = (b1s ? q8[2 * u + 1] : q8[2 * u]) + recv;
    }
    float q2[2];
#pragma unroll
    for (int u = 0; u < 2; ++u) {
      float sent = b2s ? q4[2 * u] : q4[2 * u + 1];
      float recv = __shfl_xor(sent, 4, 64);
      q2[u] = (b2s ? q4[2 * u + 1] : q4[2 * u]) + recv;
    }
    float sent = b3s ? q2[0] : q2[1];
    float recv = __shfl_xor(sent, 8, 64);
    float v = (b3s ? q2[1] : q2[0]) + recv;  // slot == m16

    int row = wm * 128 + i * 16 + q * 4 + (m16 >> 2);  // reg_sel = m16>>2
    allsums[wn * 1024 + row * 4 + (m16 & 3)] = v;      // t_sel = m16&3
  }
  __syncthreads();

  // combine the 4 wn-quarters, apply gate, atomic-accumulate into out.
  {
    float2 s = *reinterpret_cast<float2*>(&allsums[0 * 1024 + tid * 2]);
    float2 x1 = *reinterpret_cast<float2*>(&allsums[1 * 1024 + tid * 2]);
    float2 x2 = *reinterpret_cast<float2*>(&allsums[2 * 1024 + tid * 2]);
    float2 x3 = *reinterpret_cast<float2*>(&allsums[3 * 1024 + tid * 2]);
    s.x += x1.x + x2.x + x3.x;
    s.y += x1.y + x2.y + x3.y;
#pragma unroll
    for (int oi = 0; oi < 2; ++oi) {
      int o = tid * 2 + oi;  // 1024 = 256 rows x 4 t
      int row = o >> 2, t = o & 3;
      float sv = oi ? s.y : s.x;
      size_t b = m0 + row;
      float gv = g[b * 64 + t * 16 + e_idx];
      atomicAdd(&out[(size_t)t * B_ + b], gv * sv);
    }
  }
}

extern "C" void kernel_launch(void* const* d_in, const int* in_sizes, int n_in,
                              void* d_out, int out_size, void* d_ws, size_t ws_size,
                              hipStream_t stream) {
  const float* x = (const float*)d_in[0];   // [B, I]
  const float* We = (const float*)d_in[1];  // [E, H, I]
  const float* be = (const float*)d_in[2];  // [E, H]
  const float* Wg = (const float*)d_in[3];  // [T, E, I]
  const float* bg = (const float*)d_in[4];  // [T, E]
  const float* Wf = (const float*)d_in[5];  // [T, H]
  const float* bf = (const float*)d_in[6];  // [T]
  float* out = (float*)d_out;               // [T, B, 1]

  // ws: xb (16.8MB) | wb (16.8MB) | wgb (0.13MB) | g (2.1MB)
  unsigned short* xb = (unsigned short*)d_ws;
  unsigned short* wb = xb + (size_t)B_ * K_;
  unsigned short* wgb = wb + (size_t)N_ * K_;
  float* g = (float*)(wgb + (size_t)64 * K_);

  // opt-in for 128 KiB dynamic LDS (host-side, not a stream op: capture-safe)
  hipFuncSetAttribute((const void*)moe_main_kernel,
                      hipFuncAttributeMaxDynamicSharedMemorySize, 131072);

  cvt3_kernel<<<(N4X + N4W + N4G + 255) / 256, 256, 0, stream>>>(x, We, Wg, bf, xb, wb, wgb, out);
  logits_softmax_kernel<<<B_ / 128, 256, 0, stream>>>(xb, wgb, bg, g);
  dim3 grid(B_ / 256, N_ / 256);  // x = mb (disjoint out rows among concurrent blocks)
  moe_main_kernel<<<grid, 512, 131072, stream>>>(xb, wb, be, Wf, g, out);
}